// Round 7
// baseline (1764.149 us; speedup 1.0000x reference)
//
#include <hip/hip_runtime.h>
#include <math.h>

constexpr int NB = 32, NT = 64, ND = 32, NH = 256, NZ = 64, NG = 768;

// ---- ws layout (float offsets; u16 regions noted) --------------------------
constexpr long long OFF_HENC  = 0;                                // [32][256] f32
constexpr long long OFF_H0    = OFF_HENC + NB * NH;               // [32][256] f32
constexpr long long OFF_BCMB  = OFF_H0 + NB * NH;                 // [32d][2][256]
constexpr long long OFF_BIN   = OFF_BCMB + ND * 2 * NH;           // [32d][256]
constexpr long long OFF_BHN   = OFF_BIN + ND * NH;                // [32d][256]
constexpr long long OFF_EBC   = OFF_BHN + ND * NH;                // enc biases [4][256]
constexpr long long OFF_WHH2  = OFF_EBC + 1024;                   // u16: [32][768][256] plain bf16
constexpr long long OFF_WC2   = OFF_WHH2 + (long long)32 * 768 * 256 / 2; // u16: [32][768][32] swz
constexpr long long OFF_EWHH2 = OFF_WC2 + (long long)32 * 768 * 32 / 2;   // u16: [768][256] plain
constexpr long long OFF_EWI3  = OFF_EWHH2 + 768 * 256 / 2;        // u16: [768][32] swz
constexpr long long OFF_DINIMG= OFF_EWI3 + 768 * 32 / 2;          // u16: 64 x 1024 swz pages
constexpr long long OFF_EXIMG = OFF_DINIMG + 64 * 1024 / 2;       // u16: 64 x 1024
constexpr long long WS_FLOATS = OFF_EXIMG + 64 * 1024 / 2;        // ~15.1 MB

typedef __attribute__((ext_vector_type(8))) short bf16x8;
typedef __attribute__((ext_vector_type(4))) float f32x4;

__device__ __forceinline__ float sigm(float x) { return 1.f / (1.f + __expf(-x)); }
__device__ __forceinline__ ushort f2b(float x) {
  unsigned u = __float_as_uint(x);
  unsigned r = (u + 0x7FFFu + ((u >> 16) & 1u)) >> 16;
  return (ushort)r;
}

// ---------------- k_pre: plain/swz bf16 weight images + biases ---------------
__global__ void k_pre(const float* __restrict__ hWhh, const float* __restrict__ hbih,
                      const float* __restrict__ hbhh, const float* __restrict__ eWhh,
                      const float* __restrict__ eWih, const float* __restrict__ ebih,
                      const float* __restrict__ ebhh, float* __restrict__ ws) {
  int stride = gridDim.x * blockDim.x;
  int idx = blockIdx.x * blockDim.x + threadIdx.x;
  // (1) decoder Whh plain bf16 [32][768][256]
  unsigned* img = (unsigned*)(ws + OFF_WHH2);
  for (int i = idx; i < 32 * 768 * 128; i += stride) {
    int e0 = 2 * i;
    img[i] = (unsigned)f2b(hWhh[e0]) | ((unsigned)f2b(hWhh[e0 + 1]) << 16);
  }
  // (2) decoder biases
  for (int i = idx; i < ND * NH; i += stride) {
    int d = i >> 8, j = i & 255;
    const float* bi = hbih + d * NG;
    const float* bh = hbhh + d * NG;
    ws[OFF_BCMB + d * 512 + j]       = bi[j] + bh[j];
    ws[OFF_BCMB + d * 512 + 256 + j] = bi[256 + j] + bh[256 + j];
    ws[OFF_BIN + i] = bi[512 + j];
    ws[OFF_BHN + i] = bh[512 + j];
  }
  // (3) encoder Whh plain bf16 [768][256]
  unsigned* eimg = (unsigned*)(ws + OFF_EWHH2);
  for (int i = idx; i < 768 * 128; i += stride) {
    int e0 = 2 * i;
    eimg[i] = (unsigned)f2b(eWhh[e0]) | ((unsigned)f2b(eWhh[e0 + 1]) << 16);
  }
  // (4) encoder Wih swz [768][32]
  unsigned* eimg2 = (unsigned*)(ws + OFF_EWI3);
  for (int i = idx; i < 768 * 16; i += stride) {
    int byte = 4 * i;
    int g = byte >> 6;
    int nominal = byte ^ ((g & 3) << 4);
    int dd0 = (nominal & 63) >> 1;
    eimg2[i] = (unsigned)f2b(eWih[g * 32 + dd0]) | ((unsigned)f2b(eWih[g * 32 + dd0 + 1]) << 16);
  }
  // (5) encoder biases
  for (int i = idx; i < 256; i += stride) {
    ws[OFF_EBC + i]       = ebih[i] + ebhh[i];
    ws[OFF_EBC + 256 + i] = ebih[256 + i] + ebhh[256 + i];
    ws[OFF_EBC + 512 + i] = ebih[512 + i];
    ws[OFF_EBC + 768 + i] = ebhh[512 + i];
  }
}

// ---------------- k_wcomb: Wcomb[d][g][dd] -> per-head [768][32] swz image ----
__global__ __launch_bounds__(256)
void k_wcomb(const float* __restrict__ Win, const float* __restrict__ hWih,
             float* __restrict__ ws) {
  __shared__ float wd_s[32 * 257];
  __shared__ float wih_s[32 * 257];
  int blk = blockIdx.x;            // 768 = 32 d x 24 gsec
  int d = blk / 24, gsec = blk - d * 24;
  int tid = threadIdx.x;
  for (int i = tid; i < 32 * 256; i += 256) {
    int r = i >> 8, h = i & 255;
    wd_s[r * 257 + h]  = Win[((long long)(d * 32 + r)) * 256 + h];
    wih_s[r * 257 + h] = hWih[((long long)(d * NG + gsec * 32 + r)) * 256 + h];
  }
  __syncthreads();
  ushort* wcimg = (ushort*)(ws + OFF_WC2);
  for (int o = tid; o < 1024; o += 256) {
    int gl = o >> 5, dd = o & 31;
    float acc = 0.f;
    #pragma unroll 4
    for (int h = 0; h < 256; ++h) acc += wih_s[gl * 257 + h] * wd_s[dd * 257 + h];
    int g = gsec * 32 + gl;
    int off = (g * 64 + dd * 2) ^ ((g & 3) << 4);
    wcimg[d * 24576 + (off >> 1)] = f2b(acc);
  }
}

// ---------------- k_misc: din + enc-x bf16 swz pages --------------------------
__global__ void k_misc(const float* __restrict__ xp, const float* __restrict__ xc,
                       float* __restrict__ ws) {
  int idx = blockIdx.x * blockDim.x + threadIdx.x;   // 0..65535
  int i2 = idx & 32767;
  int t = i2 >> 9, lw = i2 & 511;
  int byte = lw * 4;
  int b = byte >> 6;
  int nominal = byte ^ ((b & 3) << 4);
  int dd0 = (nominal & 63) >> 1;
  if (idx < 32768) {
    float v0, v1;
    if (t == 0) { v0 = xp[(b * NT + 63) * ND + dd0]; v1 = xp[(b * NT + 63) * ND + dd0 + 1]; }
    else { v0 = xc[(b * NT + (t - 1)) * ND + dd0]; v1 = xc[(b * NT + (t - 1)) * ND + dd0 + 1]; }
    ((unsigned*)(ws + OFF_DINIMG))[i2] = (unsigned)f2b(v0) | ((unsigned)f2b(v1) << 16);
  } else {
    float v0 = xp[(b * NT + t) * ND + dd0];
    float v1 = xp[(b * NT + t) * ND + dd0 + 1];
    ((unsigned*)(ws + OFF_EXIMG))[i2] = (unsigned)f2b(v0) | ((unsigned)f2b(v1) << 16);
  }
}

// ---------------- k_enc5: 4 independent blocks x 8 batches; Whh in VGPRs ------
__global__ __launch_bounds__(256, 1)
void k_enc5(float* __restrict__ ws) {
  __shared__ __align__(16) char l_hbf[4096];
  __shared__ __align__(16) char l_x[512];
  __shared__ float rz_s[512 * 9];
  __shared__ float in_s[256 * 9];
  __shared__ float ahn_s[256 * 9];
  __shared__ float hm[8 * 260];
  __shared__ float bias_s[1024];

  const int bg = blockIdx.x;                    // 0..3 batch group
  const int tid = threadIdx.x, lane = tid & 63, w = tid >> 6;

  for (int i = tid; i < 1024; i += 256) bias_s[i] = ws[OFF_EBC + i];
  for (int o = tid; o < 2048; o += 256) {       // h=0 init (master + bf16)
    int b = o >> 8, j = o & 255;
    hm[b * 260 + j] = 0.f;
    int bo = (b * 512 + j * 2) ^ ((b & 7) << 4);
    *(ushort*)(l_hbf + bo) = 0;
  }

  // preload Whh A-frags: wave w owns row-tiles w*12..w*12+11
  const ushort* wimg = (const ushort*)(ws + OFF_EWHH2);
  bf16x8 wf[12][8];
  {
    int rowA = (w * 12) * 16 + (lane & 15);
    int kob = (lane >> 4) * 8;
    #pragma unroll
    for (int r = 0; r < 12; ++r)
      #pragma unroll
      for (int kc = 0; kc < 8; ++kc)
        wf[r][kc] = *(const bf16x8*)(wimg + (rowA + r * 16) * 256 + kc * 32 + kob);
  }
  __syncthreads();

  const char* wi_img = (const char*)((const ushort*)(ws + OFF_EWI3));
  const int colL = lane & 15;
  const int rowB = lane & 7;
  const int kb16 = (lane >> 4) * 16;

  for (int t = 0; t < 64; ++t) {
    if (tid >= 224) {    // wave 3 stages x_t sub-page (512B)
      int c = tid - 224;
      ((uint4*)l_x)[c] = ((const uint4*)((const char*)(ws + OFF_EXIMG) + t * 2048 + bg * 512))[c];
    }
    __syncthreads();

    bf16x8 bf[8];
    #pragma unroll
    for (int kc = 0; kc < 8; ++kc)
      bf[kc] = *(const bf16x8*)(l_hbf + ((rowB * 512 + kc * 64 + kb16) ^ (rowB << 4)));
    bf16x8 bx = *(const bf16x8*)(l_x + ((rowB * 64 + kb16) ^ ((rowB & 3) << 4)));

    #pragma unroll
    for (int r = 0; r < 12; ++r) {
      int rt = w * 12 + r;
      f32x4 ah = {0.f, 0.f, 0.f, 0.f};
      #pragma unroll
      for (int kc = 0; kc < 8; ++kc)
        ah = __builtin_amdgcn_mfma_f32_16x16x32_bf16(wf[r][kc], bf[kc], ah, 0, 0, 0);
      int gA = rt * 16 + colL;
      f32x4 zero = {0.f, 0.f, 0.f, 0.f};
      bf16x8 aw = *(const bf16x8*)(wi_img + ((gA * 64 + kb16) ^ ((gA & 3) << 4)));
      f32x4 ai = __builtin_amdgcn_mfma_f32_16x16x32_bf16(aw, bx, zero, 0, 0, 0);
      if (colL < 8) {
        int r0 = rt * 16 + (lane >> 4) * 4;
        #pragma unroll
        for (int rg = 0; rg < 4; ++rg) {
          int g = r0 + rg;
          if (g < 512) rz_s[g * 9 + colL] = ah[rg] + ai[rg];
          else { in_s[(g - 512) * 9 + colL] = ai[rg]; ahn_s[(g - 512) * 9 + colL] = ah[rg]; }
        }
      }
    }
    __syncthreads();

    #pragma unroll
    for (int b = 0; b < 8; ++b) {
      int j = tid;
      float pr = rz_s[j * 9 + b] + bias_s[j];
      float pz = rz_s[(256 + j) * 9 + b] + bias_s[256 + j];
      float pni = in_s[j * 9 + b] + bias_s[512 + j];
      float pnh = ahn_s[j * 9 + b] + bias_s[768 + j];
      float r = sigm(pr), u = sigm(pz);
      float n = tanhf(pni + r * pnh);
      float hold = hm[b * 260 + j];
      float hv = (1.f - u) * n + u * hold;
      hm[b * 260 + j] = hv;
      int bo = (b * 512 + j * 2) ^ ((b & 7) << 4);
      *(ushort*)(l_hbf + bo) = f2b(hv);
    }
    __syncthreads();
  }
  for (int o = tid; o < 2048; o += 256) {
    int b = o >> 8, j = o & 255;
    ws[OFF_HENC + (bg * 8 + b) * 256 + j] = hm[b * 260 + j];
  }
}

// ---------------- latent ------------------------------------------------------
__global__ __launch_bounds__(256)
void k_latent(const float* __restrict__ muw, const float* __restrict__ mub,
              const float* __restrict__ lsw, const float* __restrict__ lsb,
              const float* __restrict__ refw, const float* __restrict__ refb,
              const float* __restrict__ eps, float* __restrict__ ws,
              float* __restrict__ out) {
  __shared__ float hs[NH];
  __shared__ float mu_s[NZ];
  __shared__ float ls_s[NZ];
  __shared__ float zs[NZ];
  int b = blockIdx.x, tid = threadIdx.x;
  hs[tid] = ws[OFF_HENC + b * NH + tid];
  __syncthreads();
  if (tid < 128) {
    int zi = tid & 63;
    const float* w = (tid < 64 ? muw : lsw) + zi * NH;
    float acc = 0.f;
    #pragma unroll 4
    for (int k = 0; k < NH; ++k) acc += w[k] * hs[k];
    if (tid < 64) {
      acc += mub[zi];
      out[NB * NT * ND + b * NZ + zi] = acc;
      mu_s[zi] = acc;
    } else {
      acc += lsb[zi];
      out[NB * NT * ND + NB * NZ + b * NZ + zi] = acc;
      ls_s[zi] = acc;
    }
  }
  __syncthreads();
  if (tid < 64) zs[tid] = mu_s[tid] + eps[b * NZ + tid] * __expf(ls_s[tid]);
  __syncthreads();
  {
    const float* w = refw + tid * NZ;
    float acc = 0.f;
    #pragma unroll 4
    for (int q = 0; q < NZ; ++q) acc += w[q] * zs[q];
    ws[OFF_H0 + b * NH + tid] = tanhf(acc + refb[tid]);
  }
}

// ---------------- k_dec5: 128 independent blocks (32 heads x 4 batch-groups) --
__global__ __launch_bounds__(256, 1)
void k_dec5(const float* __restrict__ fcw, const float* __restrict__ fcb,
            float* __restrict__ ws, float* __restrict__ out) {
  __shared__ __align__(16) char l_wc[49152];
  __shared__ __align__(16) char l_hbf[4096];
  __shared__ __align__(16) char l_din[512];
  __shared__ float rz_s[512 * 9];
  __shared__ float in_s[256 * 9];
  __shared__ float ahn_s[256 * 9];
  __shared__ float hn_s[256 * 9];
  __shared__ float hm[8 * 260];
  __shared__ float bias_s[1280];

  const int d = blockIdx.x & 31, bg = blockIdx.x >> 5;
  const int tid = threadIdx.x, lane = tid & 63, w = tid >> 6;

  { // stage Wcomb page (49KB) + biases + fc weights
    const uint4* sc = (const uint4*)((const ushort*)(ws + OFF_WC2) + d * 24576);
    for (int i = tid; i < 3072; i += 256) ((uint4*)l_wc)[i] = sc[i];
    for (int i = tid; i < 1280; i += 256)
      bias_s[i] = (i < 512)  ? ws[OFF_BCMB + d * 512 + i]
                : (i < 768)  ? ws[OFF_BIN + d * 256 + (i - 512)]
                : (i < 1024) ? ws[OFF_BHN + d * 256 + (i - 768)]
                             : fcw[d * 256 + (i - 1024)];
  }
  for (int o = tid; o < 2048; o += 256) {       // h0 init
    int b = o >> 8, j = o & 255;
    float v = ws[OFF_H0 + (bg * 8 + b) * 256 + j];
    hm[b * 260 + j] = v;
    int bo = (b * 512 + j * 2) ^ ((b & 7) << 4);
    *(ushort*)(l_hbf + bo) = f2b(v);
  }

  // preload Whh A-frags
  const ushort* wimg = (const ushort*)(ws + OFF_WHH2) + (long long)d * 196608;
  bf16x8 wf[12][8];
  {
    int rowA = (w * 12) * 16 + (lane & 15);
    int kob = (lane >> 4) * 8;
    #pragma unroll
    for (int r = 0; r < 12; ++r)
      #pragma unroll
      for (int kc = 0; kc < 8; ++kc)
        wf[r][kc] = *(const bf16x8*)(wimg + (rowA + r * 16) * 256 + kc * 32 + kob);
  }
  const float fcbd = fcb[d];
  __syncthreads();

  const int colL = lane & 15;
  const int rowB = lane & 7;
  const int kb16 = (lane >> 4) * 16;

  for (int t = 0; t < 64; ++t) {
    if (tid >= 224) {    // wave 3 stages din sub-page (512B)
      int c = tid - 224;
      ((uint4*)l_din)[c] = ((const uint4*)((const char*)(ws + OFF_DINIMG) + t * 2048 + bg * 512))[c];
    }
    __syncthreads();

    bf16x8 bf[8];
    #pragma unroll
    for (int kc = 0; kc < 8; ++kc)
      bf[kc] = *(const bf16x8*)(l_hbf + ((rowB * 512 + kc * 64 + kb16) ^ (rowB << 4)));
    bf16x8 bx = *(const bf16x8*)(l_din + ((rowB * 64 + kb16) ^ ((rowB & 3) << 4)));

    #pragma unroll
    for (int r = 0; r < 12; ++r) {
      int rt = w * 12 + r;
      f32x4 ah = {0.f, 0.f, 0.f, 0.f};
      #pragma unroll
      for (int kc = 0; kc < 8; ++kc)
        ah = __builtin_amdgcn_mfma_f32_16x16x32_bf16(wf[r][kc], bf[kc], ah, 0, 0, 0);
      int gA = rt * 16 + colL;
      f32x4 zero = {0.f, 0.f, 0.f, 0.f};
      bf16x8 aw = *(const bf16x8*)(l_wc + ((gA * 64 + kb16) ^ ((gA & 3) << 4)));
      f32x4 ai = __builtin_amdgcn_mfma_f32_16x16x32_bf16(aw, bx, zero, 0, 0, 0);
      if (colL < 8) {
        int r0 = rt * 16 + (lane >> 4) * 4;
        #pragma unroll
        for (int rg = 0; rg < 4; ++rg) {
          int g = r0 + rg;
          if (g < 512) rz_s[g * 9 + colL] = ah[rg] + ai[rg];
          else { in_s[(g - 512) * 9 + colL] = ai[rg]; ahn_s[(g - 512) * 9 + colL] = ah[rg]; }
        }
      }
    }
    __syncthreads();

    #pragma unroll
    for (int b = 0; b < 8; ++b) {
      int j = tid;
      float pr = rz_s[j * 9 + b] + bias_s[j];
      float pz = rz_s[(256 + j) * 9 + b] + bias_s[256 + j];
      float pni = in_s[j * 9 + b] + bias_s[512 + j];
      float pnh = ahn_s[j * 9 + b] + bias_s[768 + j];
      float r = sigm(pr), u = sigm(pz);
      float n = tanhf(pni + r * pnh);
      float hold = hm[b * 260 + j];
      float hv = (1.f - u) * n + u * hold;
      hm[b * 260 + j] = hv;
      hn_s[j * 9 + b] = hv;
      int bo = (b * 512 + j * 2) ^ ((b & 7) << 4);
      *(ushort*)(l_hbf + bo) = f2b(hv);
    }
    __syncthreads();

    if (tid < 64) {      // fc: wave 0; 8-lane groups per batch
      int b = tid >> 3, c = tid & 7;
      float p = 0.f;
      #pragma unroll
      for (int q = 0; q < 32; ++q) {
        int j = c * 32 + q;
        p += hn_s[j * 9 + b] * bias_s[1024 + j];
      }
      p += __shfl_down(p, 4);
      p += __shfl_down(p, 2);
      p += __shfl_down(p, 1);
      if (c == 0) out[((bg * 8 + b) * NT + t) * ND + d] = p + fcbd;
    }
  }
}

extern "C" void kernel_launch(void* const* d_in, const int* in_sizes, int n_in,
                              void* d_out, int out_size, void* d_ws, size_t ws_size,
                              hipStream_t stream) {
  const float* x_past = (const float*)d_in[0];
  const float* x_curr = (const float*)d_in[1];
  const float* eps    = (const float*)d_in[2];
  const float* eWih   = (const float*)d_in[3];
  const float* ebih   = (const float*)d_in[4];
  const float* eWhh   = (const float*)d_in[5];
  const float* ebhh   = (const float*)d_in[6];
  const float* muw    = (const float*)d_in[7];
  const float* mub    = (const float*)d_in[8];
  const float* lsw    = (const float*)d_in[9];
  const float* lsb    = (const float*)d_in[10];
  const float* refw   = (const float*)d_in[11];
  const float* refb   = (const float*)d_in[12];
  const float* Win    = (const float*)d_in[13];
  const float* hWih   = (const float*)d_in[14];
  const float* hbih   = (const float*)d_in[15];
  const float* hWhh   = (const float*)d_in[16];
  const float* hbhh   = (const float*)d_in[17];
  const float* fcw    = (const float*)d_in[18];
  const float* fcb    = (const float*)d_in[19];
  float* ws  = (float*)d_ws;
  float* out = (float*)d_out;

  if (ws_size < (size_t)WS_FLOATS * 4) return;

  k_pre   <<<2048, 256, 0, stream>>>(hWhh, hbih, hbhh, eWhh, eWih, ebih, ebhh, ws);
  k_wcomb <<<768, 256, 0, stream>>>(Win, hWih, ws);
  k_misc  <<<256, 256, 0, stream>>>(x_past, x_curr, ws);
  k_enc5  <<<4, 256, 0, stream>>>(ws);
  k_latent<<<NB, 256, 0, stream>>>(muw, mub, lsw, lsb, refw, refb, eps, ws, out);
  k_dec5  <<<128, 256, 0, stream>>>(fcw, fcb, ws, out);
}

// Round 8
// 853.130 us; speedup vs baseline: 2.0679x; 2.0679x over previous
//
#include <hip/hip_runtime.h>
#include <math.h>

constexpr int NB = 32, NT = 64, ND = 32, NH = 256, NZ = 64, NG = 768;

// ---- ws layout (float offsets; u16 regions noted) --------------------------
constexpr long long OFF_HENC  = 0;                                // [32][256] f32
constexpr long long OFF_H0    = OFF_HENC + NB * NH;               // [32][256] f32
constexpr long long OFF_BCMB  = OFF_H0 + NB * NH;                 // [32d][2][256]
constexpr long long OFF_BIN   = OFF_BCMB + ND * 2 * NH;           // [32d][256]
constexpr long long OFF_BHN   = OFF_BIN + ND * NH;                // [32d][256]
constexpr long long OFF_EBC   = OFF_BHN + ND * NH;                // enc biases [4][256]
constexpr long long OFF_WHH2  = OFF_EBC + 1024;                   // u16: [32][768][256] plain bf16
constexpr long long OFF_WC2   = OFF_WHH2 + (long long)32 * 768 * 256 / 2; // u16: [32][768][32] swz
constexpr long long OFF_EWHH2 = OFF_WC2 + (long long)32 * 768 * 32 / 2;   // u16: [768][256] plain
constexpr long long OFF_EWI3  = OFF_EWHH2 + 768 * 256 / 2;        // u16: [768][32] swz
constexpr long long OFF_DINIMG= OFF_EWI3 + 768 * 32 / 2;          // u16: 64 x 1024 swz pages
constexpr long long OFF_EXIMG = OFF_DINIMG + 64 * 1024 / 2;       // u16: 64 x 1024
constexpr long long WS_FLOATS = OFF_EXIMG + 64 * 1024 / 2;        // ~15.1 MB

typedef __attribute__((ext_vector_type(8))) short bf16x8;
typedef __attribute__((ext_vector_type(4))) float f32x4;

__device__ __forceinline__ float sigm(float x) { return 1.f / (1.f + __expf(-x)); }
__device__ __forceinline__ ushort f2b(float x) {
  unsigned u = __float_as_uint(x);
  unsigned r = (u + 0x7FFFu + ((u >> 16) & 1u)) >> 16;
  return (ushort)r;
}

// ---------------- k_pre: plain/swz bf16 weight images + biases ---------------
__global__ void k_pre(const float* __restrict__ hWhh, const float* __restrict__ hbih,
                      const float* __restrict__ hbhh, const float* __restrict__ eWhh,
                      const float* __restrict__ eWih, const float* __restrict__ ebih,
                      const float* __restrict__ ebhh, float* __restrict__ ws) {
  int stride = gridDim.x * blockDim.x;
  int idx = blockIdx.x * blockDim.x + threadIdx.x;
  unsigned* img = (unsigned*)(ws + OFF_WHH2);
  for (int i = idx; i < 32 * 768 * 128; i += stride) {
    int e0 = 2 * i;
    img[i] = (unsigned)f2b(hWhh[e0]) | ((unsigned)f2b(hWhh[e0 + 1]) << 16);
  }
  for (int i = idx; i < ND * NH; i += stride) {
    int d = i >> 8, j = i & 255;
    const float* bi = hbih + d * NG;
    const float* bh = hbhh + d * NG;
    ws[OFF_BCMB + d * 512 + j]       = bi[j] + bh[j];
    ws[OFF_BCMB + d * 512 + 256 + j] = bi[256 + j] + bh[256 + j];
    ws[OFF_BIN + i] = bi[512 + j];
    ws[OFF_BHN + i] = bh[512 + j];
  }
  unsigned* eimg = (unsigned*)(ws + OFF_EWHH2);
  for (int i = idx; i < 768 * 128; i += stride) {
    int e0 = 2 * i;
    eimg[i] = (unsigned)f2b(eWhh[e0]) | ((unsigned)f2b(eWhh[e0 + 1]) << 16);
  }
  unsigned* eimg2 = (unsigned*)(ws + OFF_EWI3);
  for (int i = idx; i < 768 * 16; i += stride) {
    int byte = 4 * i;
    int g = byte >> 6;
    int nominal = byte ^ ((g & 3) << 4);
    int dd0 = (nominal & 63) >> 1;
    eimg2[i] = (unsigned)f2b(eWih[g * 32 + dd0]) | ((unsigned)f2b(eWih[g * 32 + dd0 + 1]) << 16);
  }
  for (int i = idx; i < 256; i += stride) {
    ws[OFF_EBC + i]       = ebih[i] + ebhh[i];
    ws[OFF_EBC + 256 + i] = ebih[256 + i] + ebhh[256 + i];
    ws[OFF_EBC + 512 + i] = ebih[512 + i];
    ws[OFF_EBC + 768 + i] = ebhh[512 + i];
  }
}

// ---------------- k_wcomb: Wcomb[d][g][dd] -> per-head [768][32] swz image ----
__global__ __launch_bounds__(256)
void k_wcomb(const float* __restrict__ Win, const float* __restrict__ hWih,
             float* __restrict__ ws) {
  __shared__ float wd_s[32 * 257];
  __shared__ float wih_s[32 * 257];
  int blk = blockIdx.x;            // 768 = 32 d x 24 gsec
  int d = blk / 24, gsec = blk - d * 24;
  int tid = threadIdx.x;
  for (int i = tid; i < 32 * 256; i += 256) {
    int r = i >> 8, h = i & 255;
    wd_s[r * 257 + h]  = Win[((long long)(d * 32 + r)) * 256 + h];
    wih_s[r * 257 + h] = hWih[((long long)(d * NG + gsec * 32 + r)) * 256 + h];
  }
  __syncthreads();
  ushort* wcimg = (ushort*)(ws + OFF_WC2);
  for (int o = tid; o < 1024; o += 256) {
    int gl = o >> 5, dd = o & 31;
    float acc = 0.f;
    #pragma unroll 4
    for (int h = 0; h < 256; ++h) acc += wih_s[gl * 257 + h] * wd_s[dd * 257 + h];
    int g = gsec * 32 + gl;
    int off = (g * 64 + dd * 2) ^ ((g & 3) << 4);
    wcimg[d * 24576 + (off >> 1)] = f2b(acc);
  }
}

// ---------------- k_misc: din + enc-x bf16 swz pages --------------------------
__global__ void k_misc(const float* __restrict__ xp, const float* __restrict__ xc,
                       float* __restrict__ ws) {
  int idx = blockIdx.x * blockDim.x + threadIdx.x;   // 0..65535
  int i2 = idx & 32767;
  int t = i2 >> 9, lw = i2 & 511;
  int byte = lw * 4;
  int b = byte >> 6;
  int nominal = byte ^ ((b & 3) << 4);
  int dd0 = (nominal & 63) >> 1;
  if (idx < 32768) {
    float v0, v1;
    if (t == 0) { v0 = xp[(b * NT + 63) * ND + dd0]; v1 = xp[(b * NT + 63) * ND + dd0 + 1]; }
    else { v0 = xc[(b * NT + (t - 1)) * ND + dd0]; v1 = xc[(b * NT + (t - 1)) * ND + dd0 + 1]; }
    ((unsigned*)(ws + OFF_DINIMG))[i2] = (unsigned)f2b(v0) | ((unsigned)f2b(v1) << 16);
  } else {
    float v0 = xp[(b * NT + t) * ND + dd0];
    float v1 = xp[(b * NT + t) * ND + dd0 + 1];
    ((unsigned*)(ws + OFF_EXIMG))[i2] = (unsigned)f2b(v0) | ((unsigned)f2b(v1) << 16);
  }
}

// ================= shared GRU step engine (8 waves, 6 rt/wave) ================
// Wave w owns row-tiles {16*sec + 2w + p}, sec=0..2 (r,z,n), p=0..1.
// wf: 48 A-frags in VGPRs (192). gh kc-loop -> 6 accs; gi applied post-loop.
// B rows: 8 real batches, lanes colL>=8 duplicate (outputs discarded).

// ---------------- k_enc6: 4 blocks x 8 batches --------------------------------
__global__ __launch_bounds__(512, 1)
void k_enc6(float* __restrict__ ws) {
  __shared__ __align__(16) char l_wc[49152];
  __shared__ __align__(16) char l_hbf[4096];
  __shared__ __align__(16) char l_x[512];
  __shared__ float rz_s[512 * 9];
  __shared__ float in_s[256 * 9];
  __shared__ float ahn_s[256 * 9];
  __shared__ float hm[8 * 260];
  __shared__ float bias_s[1024];

  const int bg = blockIdx.x;
  const int tid = threadIdx.x, lane = tid & 63, w = tid >> 6;

  { // stage Wih swz page + biases
    const uint4* sc = (const uint4*)((const ushort*)(ws + OFF_EWI3));
    for (int i = tid; i < 3072; i += 512) ((uint4*)l_wc)[i] = sc[i];
    for (int i = tid; i < 1024; i += 512) bias_s[i] = ws[OFF_EBC + i];
  }
  for (int o = tid; o < 2048; o += 512) {       // h=0 init
    int b = o >> 8, j = o & 255;
    hm[b * 260 + j] = 0.f;
    int bo = (b * 512 + j * 2) ^ ((b & 7) << 4);
    *(ushort*)(l_hbf + bo) = 0;
  }

  // preload Whh A-frags (192 VGPR)
  const ushort* wimg = (const ushort*)(ws + OFF_EWHH2);
  bf16x8 wf[6][8];
  {
    const int kob = (lane >> 4) * 8;
    #pragma unroll
    for (int u = 0; u < 6; ++u) {
      int rt = 16 * (u >> 1) + 2 * w + (u & 1);
      int row = rt * 16 + (lane & 15);
      #pragma unroll
      for (int kc = 0; kc < 8; ++kc)
        wf[u][kc] = *(const bf16x8*)(wimg + row * 256 + kc * 32 + kob);
    }
  }
  __syncthreads();

  const int colL = lane & 15;
  const int rowB = lane & 7;
  const int kb16 = (lane >> 4) * 16;

  for (int t = 0; t < 64; ++t) {
    if (tid >= 480) {    // last wave-part stages x sub-page (512B)
      int c = tid - 480;
      ((uint4*)l_x)[c] = ((const uint4*)((const char*)(ws + OFF_EXIMG) + t * 2048 + bg * 512))[c];
    }
    __syncthreads();

    f32x4 acc[6];
    #pragma unroll
    for (int u = 0; u < 6; ++u) acc[u] = (f32x4){0.f, 0.f, 0.f, 0.f};
    #pragma unroll
    for (int kc = 0; kc < 8; ++kc) {
      bf16x8 bf = *(const bf16x8*)(l_hbf + ((rowB * 512 + kc * 64 + kb16) ^ (rowB << 4)));
      #pragma unroll
      for (int u = 0; u < 6; ++u)
        acc[u] = __builtin_amdgcn_mfma_f32_16x16x32_bf16(wf[u][kc], bf, acc[u], 0, 0, 0);
    }
    bf16x8 bx = *(const bf16x8*)(l_x + ((rowB * 64 + kb16) ^ ((rowB & 3) << 4)));
    #pragma unroll
    for (int u = 0; u < 6; ++u) {
      int rt = 16 * (u >> 1) + 2 * w + (u & 1);
      int gA = rt * 16 + colL;
      f32x4 zero = {0.f, 0.f, 0.f, 0.f};
      bf16x8 aw = *(const bf16x8*)(l_wc + ((gA * 64 + kb16) ^ ((gA & 3) << 4)));
      f32x4 ai = __builtin_amdgcn_mfma_f32_16x16x32_bf16(aw, bx, zero, 0, 0, 0);
      if (colL < 8) {
        int r0 = rt * 16 + (lane >> 4) * 4;
        #pragma unroll
        for (int rg = 0; rg < 4; ++rg) {
          int g = r0 + rg;
          if (u < 4) rz_s[g * 9 + colL] = acc[u][rg] + ai[rg];
          else { in_s[(g - 512) * 9 + colL] = ai[rg]; ahn_s[(g - 512) * 9 + colL] = acc[u][rg]; }
        }
      }
    }
    __syncthreads();

    #pragma unroll
    for (int it = 0; it < 4; ++it) {
      int o = it * 512 + tid;
      int b = o >> 8, j = o & 255;
      float pr = rz_s[j * 9 + b] + bias_s[j];
      float pz = rz_s[(256 + j) * 9 + b] + bias_s[256 + j];
      float pni = in_s[j * 9 + b] + bias_s[512 + j];
      float pnh = ahn_s[j * 9 + b] + bias_s[768 + j];
      float r = sigm(pr), u = sigm(pz);
      float n = tanhf(pni + r * pnh);
      float hold = hm[b * 260 + j];
      float hv = (1.f - u) * n + u * hold;
      hm[b * 260 + j] = hv;
      int bo = (b * 512 + j * 2) ^ ((b & 7) << 4);
      *(ushort*)(l_hbf + bo) = f2b(hv);
    }
    __syncthreads();
  }
  for (int o = tid; o < 2048; o += 512) {
    int b = o >> 8, j = o & 255;
    ws[OFF_HENC + (bg * 8 + b) * 256 + j] = hm[b * 260 + j];
  }
}

// ---------------- latent ------------------------------------------------------
__global__ __launch_bounds__(256)
void k_latent(const float* __restrict__ muw, const float* __restrict__ mub,
              const float* __restrict__ lsw, const float* __restrict__ lsb,
              const float* __restrict__ refw, const float* __restrict__ refb,
              const float* __restrict__ eps, float* __restrict__ ws,
              float* __restrict__ out) {
  __shared__ float hs[NH];
  __shared__ float mu_s[NZ];
  __shared__ float ls_s[NZ];
  __shared__ float zs[NZ];
  int b = blockIdx.x, tid = threadIdx.x;
  hs[tid] = ws[OFF_HENC + b * NH + tid];
  __syncthreads();
  if (tid < 128) {
    int zi = tid & 63;
    const float* w = (tid < 64 ? muw : lsw) + zi * NH;
    float acc = 0.f;
    #pragma unroll 4
    for (int k = 0; k < NH; ++k) acc += w[k] * hs[k];
    if (tid < 64) {
      acc += mub[zi];
      out[NB * NT * ND + b * NZ + zi] = acc;
      mu_s[zi] = acc;
    } else {
      acc += lsb[zi];
      out[NB * NT * ND + NB * NZ + b * NZ + zi] = acc;
      ls_s[zi] = acc;
    }
  }
  __syncthreads();
  if (tid < 64) zs[tid] = mu_s[tid] + eps[b * NZ + tid] * __expf(ls_s[tid]);
  __syncthreads();
  {
    const float* w = refw + tid * NZ;
    float acc = 0.f;
    #pragma unroll 4
    for (int q = 0; q < 64; ++q) acc += w[q] * zs[q];
    ws[OFF_H0 + b * NH + tid] = tanhf(acc + refb[tid]);
  }
}

// ---------------- k_dec6: 128 blocks (32 heads x 4 batch-groups) --------------
__global__ __launch_bounds__(512, 1)
void k_dec6(const float* __restrict__ fcw, const float* __restrict__ fcb,
            float* __restrict__ ws, float* __restrict__ out) {
  __shared__ __align__(16) char l_wc[49152];
  __shared__ __align__(16) char l_hbf[4096];
  __shared__ __align__(16) char l_din[512];
  __shared__ float rz_s[512 * 9];
  __shared__ float in_s[256 * 9];
  __shared__ float ahn_s[256 * 9];
  __shared__ float hm[8 * 260];
  __shared__ float bias_s[1280];

  const int d = blockIdx.x & 31, bg = blockIdx.x >> 5;
  const int tid = threadIdx.x, lane = tid & 63, w = tid >> 6;

  { // stage Wcomb page + biases + fc weights
    const uint4* sc = (const uint4*)((const ushort*)(ws + OFF_WC2) + d * 24576);
    for (int i = tid; i < 3072; i += 512) ((uint4*)l_wc)[i] = sc[i];
    for (int i = tid; i < 1280; i += 512)
      bias_s[i] = (i < 512)  ? ws[OFF_BCMB + d * 512 + i]
                : (i < 768)  ? ws[OFF_BIN + d * 256 + (i - 512)]
                : (i < 1024) ? ws[OFF_BHN + d * 256 + (i - 768)]
                             : fcw[d * 256 + (i - 1024)];
  }
  for (int o = tid; o < 2048; o += 512) {       // h0 init
    int b = o >> 8, j = o & 255;
    float v = ws[OFF_H0 + (bg * 8 + b) * 256 + j];
    hm[b * 260 + j] = v;
    int bo = (b * 512 + j * 2) ^ ((b & 7) << 4);
    *(ushort*)(l_hbf + bo) = f2b(v);
  }

  // preload Whh A-frags (192 VGPR)
  const ushort* wimg = (const ushort*)(ws + OFF_WHH2) + (long long)d * 196608;
  bf16x8 wf[6][8];
  {
    const int kob = (lane >> 4) * 8;
    #pragma unroll
    for (int u = 0; u < 6; ++u) {
      int rt = 16 * (u >> 1) + 2 * w + (u & 1);
      int row = rt * 16 + (lane & 15);
      #pragma unroll
      for (int kc = 0; kc < 8; ++kc)
        wf[u][kc] = *(const bf16x8*)(wimg + row * 256 + kc * 32 + kob);
    }
  }
  const float fcbd = fcb[d];
  __syncthreads();

  const int colL = lane & 15;
  const int rowB = lane & 7;
  const int kb16 = (lane >> 4) * 16;

  for (int t = 0; t < 64; ++t) {
    if (tid >= 480) {
      int c = tid - 480;
      ((uint4*)l_din)[c] = ((const uint4*)((const char*)(ws + OFF_DINIMG) + t * 2048 + bg * 512))[c];
    }
    __syncthreads();

    f32x4 acc[6];
    #pragma unroll
    for (int u = 0; u < 6; ++u) acc[u] = (f32x4){0.f, 0.f, 0.f, 0.f};
    #pragma unroll
    for (int kc = 0; kc < 8; ++kc) {
      bf16x8 bf = *(const bf16x8*)(l_hbf + ((rowB * 512 + kc * 64 + kb16) ^ (rowB << 4)));
      #pragma unroll
      for (int u = 0; u < 6; ++u)
        acc[u] = __builtin_amdgcn_mfma_f32_16x16x32_bf16(wf[u][kc], bf, acc[u], 0, 0, 0);
    }
    bf16x8 bx = *(const bf16x8*)(l_din + ((rowB * 64 + kb16) ^ ((rowB & 3) << 4)));
    #pragma unroll
    for (int u = 0; u < 6; ++u) {
      int rt = 16 * (u >> 1) + 2 * w + (u & 1);
      int gA = rt * 16 + colL;
      f32x4 zero = {0.f, 0.f, 0.f, 0.f};
      bf16x8 aw = *(const bf16x8*)(l_wc + ((gA * 64 + kb16) ^ ((gA & 3) << 4)));
      f32x4 ai = __builtin_amdgcn_mfma_f32_16x16x32_bf16(aw, bx, zero, 0, 0, 0);
      if (colL < 8) {
        int r0 = rt * 16 + (lane >> 4) * 4;
        #pragma unroll
        for (int rg = 0; rg < 4; ++rg) {
          int g = r0 + rg;
          if (u < 4) rz_s[g * 9 + colL] = acc[u][rg] + ai[rg];
          else { in_s[(g - 512) * 9 + colL] = ai[rg]; ahn_s[(g - 512) * 9 + colL] = acc[u][rg]; }
        }
      }
    }
    __syncthreads();

    #pragma unroll
    for (int it = 0; it < 4; ++it) {
      int o = it * 512 + tid;
      int b = o >> 8, j = o & 255;
      float pr = rz_s[j * 9 + b] + bias_s[j];
      float pz = rz_s[(256 + j) * 9 + b] + bias_s[256 + j];
      float pni = in_s[j * 9 + b] + bias_s[512 + j];
      float pnh = ahn_s[j * 9 + b] + bias_s[768 + j];
      float r = sigm(pr), u = sigm(pz);
      float n = tanhf(pni + r * pnh);
      float hold = hm[b * 260 + j];
      float hv = (1.f - u) * n + u * hold;
      hm[b * 260 + j] = hv;
      int bo = (b * 512 + j * 2) ^ ((b & 7) << 4);
      *(ushort*)(l_hbf + bo) = f2b(hv);
    }
    __syncthreads();

    if (tid < 64) {      // fc from hm (post-gate h)
      int b = tid >> 3, c = tid & 7;
      float p = 0.f;
      #pragma unroll
      for (int q = 0; q < 32; ++q) {
        int j = c * 32 + q;
        p += hm[b * 260 + j] * bias_s[1024 + j];
      }
      p += __shfl_down(p, 4);
      p += __shfl_down(p, 2);
      p += __shfl_down(p, 1);
      if (c == 0) out[((bg * 8 + b) * NT + t) * ND + d] = p + fcbd;
    }
  }
}

extern "C" void kernel_launch(void* const* d_in, const int* in_sizes, int n_in,
                              void* d_out, int out_size, void* d_ws, size_t ws_size,
                              hipStream_t stream) {
  const float* x_past = (const float*)d_in[0];
  const float* x_curr = (const float*)d_in[1];
  const float* eps    = (const float*)d_in[2];
  const float* eWih   = (const float*)d_in[3];
  const float* ebih   = (const float*)d_in[4];
  const float* eWhh   = (const float*)d_in[5];
  const float* ebhh   = (const float*)d_in[6];
  const float* muw    = (const float*)d_in[7];
  const float* mub    = (const float*)d_in[8];
  const float* lsw    = (const float*)d_in[9];
  const float* lsb    = (const float*)d_in[10];
  const float* refw   = (const float*)d_in[11];
  const float* refb   = (const float*)d_in[12];
  const float* Win    = (const float*)d_in[13];
  const float* hWih   = (const float*)d_in[14];
  const float* hbih   = (const float*)d_in[15];
  const float* hWhh   = (const float*)d_in[16];
  const float* hbhh   = (const float*)d_in[17];
  const float* fcw    = (const float*)d_in[18];
  const float* fcb    = (const float*)d_in[19];
  float* ws  = (float*)d_ws;
  float* out = (float*)d_out;

  if (ws_size < (size_t)WS_FLOATS * 4) return;

  k_pre   <<<2048, 256, 0, stream>>>(hWhh, hbih, hbhh, eWhh, eWih, ebih, ebhh, ws);
  k_wcomb <<<768, 256, 0, stream>>>(Win, hWih, ws);
  k_misc  <<<256, 256, 0, stream>>>(x_past, x_curr, ws);
  k_enc6  <<<4, 512, 0, stream>>>(ws);
  k_latent<<<NB, 256, 0, stream>>>(muw, mub, lsw, lsb, refw, refb, eps, ws, out);
  k_dec6  <<<128, 512, 0, stream>>>(fcw, fcb, ws, out);
}

// Round 10
// 810.073 us; speedup vs baseline: 2.1778x; 1.0532x over previous
//
#include <hip/hip_runtime.h>
#include <math.h>

constexpr int NB = 32, NT = 64, ND = 32, NH = 256, NZ = 64, NG = 768;

// ---- ws layout (float offsets; u16 regions noted) --------------------------
constexpr long long OFF_HENC  = 0;                                // [32][256] f32
constexpr long long OFF_H0    = OFF_HENC + NB * NH;               // [32][256] f32
constexpr long long OFF_BCMB  = OFF_H0 + NB * NH;                 // [32d][2][256]
constexpr long long OFF_BIN   = OFF_BCMB + ND * 2 * NH;           // [32d][256]
constexpr long long OFF_BHN   = OFF_BIN + ND * NH;                // [32d][256]
constexpr long long OFF_EBC   = OFF_BHN + ND * NH;                // enc biases [4][256]
constexpr long long OFF_WHH2  = OFF_EBC + 1024;                   // u16: [32][768][256] plain bf16
constexpr long long OFF_WC2   = OFF_WHH2 + (long long)32 * 768 * 256 / 2; // u16: [32][768][32] swz
constexpr long long OFF_EWHH2 = OFF_WC2 + (long long)32 * 768 * 32 / 2;   // u16: [768][256] plain
constexpr long long OFF_EWI3  = OFF_EWHH2 + 768 * 256 / 2;        // u16: [768][32] swz
constexpr long long OFF_DINIMG= OFF_EWI3 + 768 * 32 / 2;          // u16: 64 x 1024 swz pages
constexpr long long OFF_EXIMG = OFF_DINIMG + 64 * 1024 / 2;       // u16: 64 x 1024
constexpr long long WS_FLOATS = OFF_EXIMG + 64 * 1024 / 2;        // ~15.1 MB

typedef __attribute__((ext_vector_type(8))) short bf16x8;
typedef __attribute__((ext_vector_type(4))) float f32x4;

__device__ __forceinline__ float sigm(float x) { return 1.f / (1.f + __expf(-x)); }
__device__ __forceinline__ float tanhfast(float y) {
  float e = __expf(-2.f * fabsf(y));
  float th = 1.f - 2.f * e / (1.f + e);
  return __builtin_copysignf(th, y);
}
__device__ __forceinline__ ushort f2b(float x) {
  unsigned u = __float_as_uint(x);
  unsigned r = (u + 0x7FFFu + ((u >> 16) & 1u)) >> 16;
  return (ushort)r;
}

// ---------------- k_pre: plain/swz bf16 weight images + biases ---------------
__global__ void k_pre(const float* __restrict__ hWhh, const float* __restrict__ hbih,
                      const float* __restrict__ hbhh, const float* __restrict__ eWhh,
                      const float* __restrict__ eWih, const float* __restrict__ ebih,
                      const float* __restrict__ ebhh, float* __restrict__ ws) {
  int stride = gridDim.x * blockDim.x;
  int idx = blockIdx.x * blockDim.x + threadIdx.x;
  unsigned* img = (unsigned*)(ws + OFF_WHH2);
  for (int i = idx; i < 32 * 768 * 128; i += stride) {
    int e0 = 2 * i;
    img[i] = (unsigned)f2b(hWhh[e0]) | ((unsigned)f2b(hWhh[e0 + 1]) << 16);
  }
  for (int i = idx; i < ND * NH; i += stride) {
    int d = i >> 8, j = i & 255;
    const float* bi = hbih + d * NG;
    const float* bh = hbhh + d * NG;
    ws[OFF_BCMB + d * 512 + j]       = bi[j] + bh[j];
    ws[OFF_BCMB + d * 512 + 256 + j] = bi[256 + j] + bh[256 + j];
    ws[OFF_BIN + i] = bi[512 + j];
    ws[OFF_BHN + i] = bh[512 + j];
  }
  unsigned* eimg = (unsigned*)(ws + OFF_EWHH2);
  for (int i = idx; i < 768 * 128; i += stride) {
    int e0 = 2 * i;
    eimg[i] = (unsigned)f2b(eWhh[e0]) | ((unsigned)f2b(eWhh[e0 + 1]) << 16);
  }
  unsigned* eimg2 = (unsigned*)(ws + OFF_EWI3);
  for (int i = idx; i < 768 * 16; i += stride) {
    int byte = 4 * i;
    int g = byte >> 6;
    int nominal = byte ^ ((g & 3) << 4);
    int dd0 = (nominal & 63) >> 1;
    eimg2[i] = (unsigned)f2b(eWih[g * 32 + dd0]) | ((unsigned)f2b(eWih[g * 32 + dd0 + 1]) << 16);
  }
  for (int i = idx; i < 256; i += stride) {
    ws[OFF_EBC + i]       = ebih[i] + ebhh[i];
    ws[OFF_EBC + 256 + i] = ebih[256 + i] + ebhh[256 + i];
    ws[OFF_EBC + 512 + i] = ebih[512 + i];
    ws[OFF_EBC + 768 + i] = ebhh[512 + i];
  }
}

// ---------------- k_wcomb: Wcomb[d][g][dd] -> per-head [768][32] swz image ----
__global__ __launch_bounds__(256)
void k_wcomb(const float* __restrict__ Win, const float* __restrict__ hWih,
             float* __restrict__ ws) {
  __shared__ float wd_s[32 * 257];
  __shared__ float wih_s[32 * 257];
  int blk = blockIdx.x;            // 768 = 32 d x 24 gsec
  int d = blk / 24, gsec = blk - d * 24;
  int tid = threadIdx.x;
  for (int i = tid; i < 32 * 256; i += 256) {
    int r = i >> 8, h = i & 255;
    wd_s[r * 257 + h]  = Win[((long long)(d * 32 + r)) * 256 + h];
    wih_s[r * 257 + h] = hWih[((long long)(d * NG + gsec * 32 + r)) * 256 + h];
  }
  __syncthreads();
  ushort* wcimg = (ushort*)(ws + OFF_WC2);
  for (int o = tid; o < 1024; o += 256) {
    int gl = o >> 5, dd = o & 31;
    float acc = 0.f;
    #pragma unroll 4
    for (int h = 0; h < 256; ++h) acc += wih_s[gl * 257 + h] * wd_s[dd * 257 + h];
    int g = gsec * 32 + gl;
    int off = (g * 64 + dd * 2) ^ ((g & 3) << 4);
    wcimg[d * 24576 + (off >> 1)] = f2b(acc);
  }
}

// ---------------- k_misc: din + enc-x bf16 swz pages --------------------------
__global__ void k_misc(const float* __restrict__ xp, const float* __restrict__ xc,
                       float* __restrict__ ws) {
  int idx = blockIdx.x * blockDim.x + threadIdx.x;   // 0..65535
  int i2 = idx & 32767;
  int t = i2 >> 9, lw = i2 & 511;
  int byte = lw * 4;
  int b = byte >> 6;
  int nominal = byte ^ ((b & 3) << 4);
  int dd0 = (nominal & 63) >> 1;
  if (idx < 32768) {
    float v0, v1;
    if (t == 0) { v0 = xp[(b * NT + 63) * ND + dd0]; v1 = xp[(b * NT + 63) * ND + dd0 + 1]; }
    else { v0 = xc[(b * NT + (t - 1)) * ND + dd0]; v1 = xc[(b * NT + (t - 1)) * ND + dd0 + 1]; }
    ((unsigned*)(ws + OFF_DINIMG))[i2] = (unsigned)f2b(v0) | ((unsigned)f2b(v1) << 16);
  } else {
    float v0 = xp[(b * NT + t) * ND + dd0];
    float v1 = xp[(b * NT + t) * ND + dd0 + 1];
    ((unsigned*)(ws + OFF_EXIMG))[i2] = (unsigned)f2b(v0) | ((unsigned)f2b(v1) << 16);
  }
}

// ================= GRU step engine: 8 waves, 6 rt/wave, x-series in LDS =======
// Wave w owns row-tiles {16*sec + 2w + p}, sec=0..2, p=0..1. 2 barriers/step.

// ---------------- k_enc7: 4 blocks x 8 batches --------------------------------
__global__ __launch_bounds__(512, 2)
void k_enc7(float* __restrict__ ws) {
  __shared__ __align__(16) char l_wc[49152];
  __shared__ __align__(16) char l_hbf[4096];
  __shared__ __align__(16) char l_x[32768];
  __shared__ float rz_s[512 * 9];
  __shared__ float in_s[256 * 9];
  __shared__ float ahn_s[256 * 9];
  __shared__ float hm[8 * 264];
  __shared__ float bias_s[1024];

  const int bg = blockIdx.x;
  const int tid = threadIdx.x, lane = tid & 63, w = tid >> 6;

  { // stage Wih swz page + biases + full x series (bg slice)
    const uint4* sc = (const uint4*)((const ushort*)(ws + OFF_EWI3));
    for (int i = tid; i < 3072; i += 512) ((uint4*)l_wc)[i] = sc[i];
    for (int i = tid; i < 1024; i += 512) bias_s[i] = ws[OFF_EBC + i];
    const uint4* sx = (const uint4*)((const ushort*)(ws + OFF_EXIMG));
    for (int i = tid; i < 2048; i += 512) {
      int t = i >> 5, c = i & 31;
      ((uint4*)l_x)[i] = sx[t * 128 + bg * 32 + c];
    }
  }
  for (int o = tid; o < 2048; o += 512) {       // h=0 init
    int b = o >> 8, j = o & 255;
    hm[b * 264 + j] = 0.f;
    int bo = (b * 512 + j * 2) ^ ((b & 7) << 4);
    *(ushort*)(l_hbf + bo) = 0;
  }

  // preload Whh A-frags (unified VGPR/AGPR file)
  const ushort* wimg = (const ushort*)(ws + OFF_EWHH2);
  bf16x8 wf[6][8];
  {
    const int kob = (lane >> 4) * 8;
    #pragma unroll
    for (int u = 0; u < 6; ++u) {
      int rt = 16 * (u >> 1) + 2 * w + (u & 1);
      int row = rt * 16 + (lane & 15);
      #pragma unroll
      for (int kc = 0; kc < 8; ++kc)
        wf[u][kc] = *(const bf16x8*)(wimg + row * 256 + kc * 32 + kob);
    }
  }
  __syncthreads();

  const int colL = lane & 15;
  const int rowB = lane & 7;
  const int kb16 = (lane >> 4) * 16;

  for (int t = 0; t < 64; ++t) {
    f32x4 acc[6];
    #pragma unroll
    for (int u = 0; u < 6; ++u) acc[u] = (f32x4){0.f, 0.f, 0.f, 0.f};
    #pragma unroll
    for (int kc = 0; kc < 8; ++kc) {
      bf16x8 bf = *(const bf16x8*)(l_hbf + ((rowB * 512 + kc * 64 + kb16) ^ (rowB << 4)));
      #pragma unroll
      for (int u = 0; u < 6; ++u)
        acc[u] = __builtin_amdgcn_mfma_f32_16x16x32_bf16(wf[u][kc], bf, acc[u], 0, 0, 0);
    }
    bf16x8 bx = *(const bf16x8*)(l_x + t * 512 + ((rowB * 64 + kb16) ^ ((rowB & 3) << 4)));
    #pragma unroll
    for (int u = 0; u < 6; ++u) {
      int rt = 16 * (u >> 1) + 2 * w + (u & 1);
      int gA = rt * 16 + colL;
      f32x4 zero = {0.f, 0.f, 0.f, 0.f};
      bf16x8 aw = *(const bf16x8*)(l_wc + ((gA * 64 + kb16) ^ ((gA & 3) << 4)));
      f32x4 ai = __builtin_amdgcn_mfma_f32_16x16x32_bf16(aw, bx, zero, 0, 0, 0);
      if (colL < 8) {
        int r0 = rt * 16 + (lane >> 4) * 4;
        #pragma unroll
        for (int rg = 0; rg < 4; ++rg) {
          int g = r0 + rg;
          if (u < 4) rz_s[g * 9 + colL] = acc[u][rg] + ai[rg];
          else { in_s[(g - 512) * 9 + colL] = ai[rg]; ahn_s[(g - 512) * 9 + colL] = acc[u][rg]; }
        }
      }
    }
    __syncthreads();

    #pragma unroll
    for (int it = 0; it < 4; ++it) {
      int o = it * 512 + tid;
      int b = o >> 8, j = o & 255;
      float pr = rz_s[j * 9 + b] + bias_s[j];
      float pz = rz_s[(256 + j) * 9 + b] + bias_s[256 + j];
      float pni = in_s[j * 9 + b] + bias_s[512 + j];
      float pnh = ahn_s[j * 9 + b] + bias_s[768 + j];
      float r = sigm(pr), u = sigm(pz);
      float n = tanhfast(pni + r * pnh);
      float hold = hm[b * 264 + j];
      float hv = (1.f - u) * n + u * hold;
      hm[b * 264 + j] = hv;
      int bo = (b * 512 + j * 2) ^ ((b & 7) << 4);
      *(ushort*)(l_hbf + bo) = f2b(hv);
    }
    __syncthreads();
  }
  for (int o = tid; o < 2048; o += 512) {
    int b = o >> 8, j = o & 255;
    ws[OFF_HENC + (bg * 8 + b) * 256 + j] = hm[b * 264 + j];
  }
}

// ---------------- latent ------------------------------------------------------
__global__ __launch_bounds__(256)
void k_latent(const float* __restrict__ muw, const float* __restrict__ mub,
              const float* __restrict__ lsw, const float* __restrict__ lsb,
              const float* __restrict__ refw, const float* __restrict__ refb,
              const float* __restrict__ eps, float* __restrict__ ws,
              float* __restrict__ out) {
  __shared__ float hs[NH];
  __shared__ float mu_s[NZ];
  __shared__ float ls_s[NZ];
  __shared__ float zs[NZ];
  int b = blockIdx.x, tid = threadIdx.x;
  hs[tid] = ws[OFF_HENC + b * NH + tid];
  __syncthreads();
  if (tid < 128) {
    int zi = tid & 63;
    const float* w = (tid < 64 ? muw : lsw) + zi * NH;
    float acc = 0.f;
    #pragma unroll 4
    for (int k = 0; k < NH; ++k) acc += w[k] * hs[k];
    if (tid < 64) {
      acc += mub[zi];
      out[NB * NT * ND + b * NZ + zi] = acc;
      mu_s[zi] = acc;
    } else {
      acc += lsb[zi];
      out[NB * NT * ND + NB * NZ + b * NZ + zi] = acc;
      ls_s[zi] = acc;
    }
  }
  __syncthreads();
  if (tid < 64) zs[tid] = mu_s[tid] + eps[b * NZ + tid] * __expf(ls_s[tid]);
  __syncthreads();
  {
    const float* w = refw + tid * NZ;
    float acc = 0.f;
    #pragma unroll 4
    for (int q = 0; q < 64; ++q) acc += w[q] * zs[q];
    ws[OFF_H0 + b * NH + tid] = tanhf(acc + refb[tid]);
  }
}

// ---------------- k_dec7: 128 blocks (32 heads x 4 batch-groups) --------------
__global__ __launch_bounds__(512, 2)
void k_dec7(const float* __restrict__ fcw, const float* __restrict__ fcb,
            float* __restrict__ ws, float* __restrict__ out) {
  __shared__ __align__(16) char l_wc[49152];
  __shared__ __align__(16) char l_hbf[4096];
  __shared__ __align__(16) char l_din[32768];
  __shared__ float rz_s[512 * 9];
  __shared__ float in_s[256 * 9];
  __shared__ float ahn_s[256 * 9];
  __shared__ float hm[8 * 264];
  __shared__ float bias_s[1280];

  const int d = blockIdx.x & 31, bg = blockIdx.x >> 5;
  const int tid = threadIdx.x, lane = tid & 63, w = tid >> 6;

  { // stage Wcomb page + biases + fc weights + full din series (bg slice)
    const uint4* sc = (const uint4*)((const ushort*)(ws + OFF_WC2) + d * 24576);
    for (int i = tid; i < 3072; i += 512) ((uint4*)l_wc)[i] = sc[i];
    for (int i = tid; i < 1280; i += 512)
      bias_s[i] = (i < 512)  ? ws[OFF_BCMB + d * 512 + i]
                : (i < 768)  ? ws[OFF_BIN + d * 256 + (i - 512)]
                : (i < 1024) ? ws[OFF_BHN + d * 256 + (i - 768)]
                             : fcw[d * 256 + (i - 1024)];
    const uint4* sx = (const uint4*)((const ushort*)(ws + OFF_DINIMG));
    for (int i = tid; i < 2048; i += 512) {
      int t = i >> 5, c = i & 31;
      ((uint4*)l_din)[i] = sx[t * 128 + bg * 32 + c];
    }
  }
  for (int o = tid; o < 2048; o += 512) {       // h0 init
    int b = o >> 8, j = o & 255;
    float v = ws[OFF_H0 + (bg * 8 + b) * 256 + j];
    hm[b * 264 + j] = v;
    int bo = (b * 512 + j * 2) ^ ((b & 7) << 4);
    *(ushort*)(l_hbf + bo) = f2b(v);
  }

  // preload Whh A-frags (unified VGPR/AGPR file)
  const ushort* wimg = (const ushort*)(ws + OFF_WHH2) + (long long)d * 196608;
  bf16x8 wf[6][8];
  {
    const int kob = (lane >> 4) * 8;
    #pragma unroll
    for (int u = 0; u < 6; ++u) {
      int rt = 16 * (u >> 1) + 2 * w + (u & 1);
      int row = rt * 16 + (lane & 15);
      #pragma unroll
      for (int kc = 0; kc < 8; ++kc)
        wf[u][kc] = *(const bf16x8*)(wimg + row * 256 + kc * 32 + kob);
    }
  }
  const float fcbd = fcb[d];
  __syncthreads();

  const int colL = lane & 15;
  const int rowB = lane & 7;
  const int kb16 = (lane >> 4) * 16;

  for (int t = 0; t < 64; ++t) {
    f32x4 acc[6];
    #pragma unroll
    for (int u = 0; u < 6; ++u) acc[u] = (f32x4){0.f, 0.f, 0.f, 0.f};
    #pragma unroll
    for (int kc = 0; kc < 8; ++kc) {
      bf16x8 bf = *(const bf16x8*)(l_hbf + ((rowB * 512 + kc * 64 + kb16) ^ (rowB << 4)));
      #pragma unroll
      for (int u = 0; u < 6; ++u)
        acc[u] = __builtin_amdgcn_mfma_f32_16x16x32_bf16(wf[u][kc], bf, acc[u], 0, 0, 0);
    }
    bf16x8 bx = *(const bf16x8*)(l_din + t * 512 + ((rowB * 64 + kb16) ^ ((rowB & 3) << 4)));
    #pragma unroll
    for (int u = 0; u < 6; ++u) {
      int rt = 16 * (u >> 1) + 2 * w + (u & 1);
      int gA = rt * 16 + colL;
      f32x4 zero = {0.f, 0.f, 0.f, 0.f};
      bf16x8 aw = *(const bf16x8*)(l_wc + ((gA * 64 + kb16) ^ ((gA & 3) << 4)));
      f32x4 ai = __builtin_amdgcn_mfma_f32_16x16x32_bf16(aw, bx, zero, 0, 0, 0);
      if (colL < 8) {
        int r0 = rt * 16 + (lane >> 4) * 4;
        #pragma unroll
        for (int rg = 0; rg < 4; ++rg) {
          int g = r0 + rg;
          if (u < 4) rz_s[g * 9 + colL] = acc[u][rg] + ai[rg];
          else { in_s[(g - 512) * 9 + colL] = ai[rg]; ahn_s[(g - 512) * 9 + colL] = acc[u][rg]; }
        }
      }
    }
    __syncthreads();

    #pragma unroll
    for (int it = 0; it < 4; ++it) {
      int o = it * 512 + tid;
      int b = o >> 8, j = o & 255;
      float pr = rz_s[j * 9 + b] + bias_s[j];
      float pz = rz_s[(256 + j) * 9 + b] + bias_s[256 + j];
      float pni = in_s[j * 9 + b] + bias_s[512 + j];
      float pnh = ahn_s[j * 9 + b] + bias_s[768 + j];
      float r = sigm(pr), u = sigm(pz);
      float n = tanhfast(pni + r * pnh);
      float hold = hm[b * 264 + j];
      float hv = (1.f - u) * n + u * hold;
      hm[b * 264 + j] = hv;
      int bo = (b * 512 + j * 2) ^ ((b & 7) << 4);
      *(ushort*)(l_hbf + bo) = f2b(hv);
    }
    __syncthreads();

    { // fc: wave w handles batch w; float4 conflict-free reads + shfl reduce
      float4 hv4 = *(const float4*)(hm + w * 264 + 4 * lane);
      float4 fw4 = *(const float4*)(bias_s + 1024 + 4 * lane);
      float p = hv4.x * fw4.x + hv4.y * fw4.y + hv4.z * fw4.z + hv4.w * fw4.w;
      p += __shfl_down(p, 32);
      p += __shfl_down(p, 16);
      p += __shfl_down(p, 8);
      p += __shfl_down(p, 4);
      p += __shfl_down(p, 2);
      p += __shfl_down(p, 1);
      if (lane == 0) out[((bg * 8 + w) * NT + t) * ND + d] = p + fcbd;
    }
  }
}

extern "C" void kernel_launch(void* const* d_in, const int* in_sizes, int n_in,
                              void* d_out, int out_size, void* d_ws, size_t ws_size,
                              hipStream_t stream) {
  const float* x_past = (const float*)d_in[0];
  const float* x_curr = (const float*)d_in[1];
  const float* eps    = (const float*)d_in[2];
  const float* eWih   = (const float*)d_in[3];
  const float* ebih   = (const float*)d_in[4];
  const float* eWhh   = (const float*)d_in[5];
  const float* ebhh   = (const float*)d_in[6];
  const float* muw    = (const float*)d_in[7];
  const float* mub    = (const float*)d_in[8];
  const float* lsw    = (const float*)d_in[9];
  const float* lsb    = (const float*)d_in[10];
  const float* refw   = (const float*)d_in[11];
  const float* refb   = (const float*)d_in[12];
  const float* Win    = (const float*)d_in[13];
  const float* hWih   = (const float*)d_in[14];
  const float* hbih   = (const float*)d_in[15];
  const float* hWhh   = (const float*)d_in[16];
  const float* hbhh   = (const float*)d_in[17];
  const float* fcw    = (const float*)d_in[18];
  const float* fcb    = (const float*)d_in[19];
  float* ws  = (float*)d_ws;
  float* out = (float*)d_out;

  if (ws_size < (size_t)WS_FLOATS * 4) return;

  k_pre   <<<2048, 256, 0, stream>>>(hWhh, hbih, hbhh, eWhh, eWih, ebih, ebhh, ws);
  k_wcomb <<<768, 256, 0, stream>>>(Win, hWih, ws);
  k_misc  <<<256, 256, 0, stream>>>(x_past, x_curr, ws);
  k_enc7  <<<4, 512, 0, stream>>>(ws);
  k_latent<<<NB, 256, 0, stream>>>(muw, mub, lsw, lsb, refw, refb, eps, ws, out);
  k_dec7  <<<128, 512, 0, stream>>>(fcw, fcb, ws, out);
}